// Round 3
// baseline (421.115 us; speedup 1.0000x reference)
//
#include <hip/hip_runtime.h>
#include <math.h>

// DilatedAttention on MI355X (gfx950), bf16 MFMA implementation.
// L=4096, E=1024, H=16, D=64. Branches (sl,dr) = (1024,1),(2048,2),(4096,4).
// Every branch reduces to causal attention over g=1024 sparse positions.
//
// Attention in transposed-S form:
//   S^T = K Q^T  (lane l16 = q column)  -> softmax reduces with 4 shuffles
//   O^T = V^T P^T with 16x16x16 MFMA    -> P^T registers are the B-operand,
//                                          no LDS round-trip, in-lane alpha/l.
// Double-buffered K/V staging (1 barrier/iter) and qt-descending launch.

#define L_SEQ 4096
#define EDIM  1024
#define NH    16
#define HD    64
#define GLEN  1024

typedef __bf16 bf16;
typedef __bf16 bf16x8 __attribute__((ext_vector_type(8)));
typedef __bf16 bf16x4 __attribute__((ext_vector_type(4)));
typedef short  s16x4  __attribute__((ext_vector_type(4)));
typedef float  f32x4  __attribute__((ext_vector_type(4)));

// async global->LDS, 16B per lane. LDS dest semantics: wave-uniform base + lane*16.
__device__ __forceinline__ void gload16(const bf16* g, bf16* l) {
  __builtin_amdgcn_global_load_lds(
      (__attribute__((address_space(1))) void*)(const_cast<bf16*>(g)),
      (__attribute__((address_space(3))) void*)(l),
      16, 0, 0);
}

// v_mfma_f32_16x16x16_bf16 (device pass verified on gfx950; host pass must not
// see the builtin name — it only exists in the device compilation).
__device__ __forceinline__ f32x4 mfma16x16x16_bf16(bf16x4 a, bf16x4 b, f32x4 c) {
#if defined(__HIP_DEVICE_COMPILE__)
  union { bf16x4 h; s16x4 s; } ua, ub;
  ua.h = a; ub.h = b;
  return __builtin_amdgcn_mfma_f32_16x16x16bf16_1k(ua.s, ub.s, c, 0, 0, 0);
#else
  (void)a; (void)b;
  return c;   // host stub, never executed
#endif
}

// ---------------------------------------------------------------------------
// fp32 -> bf16 conversion for query/key/value (L*E) and Wq/Wk/Wv/Wo (E*E)
// ---------------------------------------------------------------------------
__global__ __launch_bounds__(256) void cvt_kernel(
    const float* q, const float* k, const float* v,
    const float* wq, const float* wk, const float* wv, const float* wo,
    bf16* oq, bf16* ok, bf16* ov,
    bf16* owq, bf16* owk, bf16* owv, bf16* owo)
{
  const float* src; bf16* dst; int n;
  switch (blockIdx.y) {
    case 0: src = q;  dst = oq;  n = L_SEQ*EDIM; break;
    case 1: src = k;  dst = ok;  n = L_SEQ*EDIM; break;
    case 2: src = v;  dst = ov;  n = L_SEQ*EDIM; break;
    case 3: src = wq; dst = owq; n = EDIM*EDIM; break;
    case 4: src = wk; dst = owk; n = EDIM*EDIM; break;
    case 5: src = wv; dst = owv; n = EDIM*EDIM; break;
    default: src = wo; dst = owo; n = EDIM*EDIM; break;
  }
  int i = (blockIdx.x * 256 + threadIdx.x) * 8;
  if (i >= n) return;
  const float4* s4 = (const float4*)(src + i);
  float4 a = s4[0], b = s4[1];
  bf16x8 o = { (bf16)a.x, (bf16)a.y, (bf16)a.z, (bf16)a.w,
               (bf16)b.x, (bf16)b.y, (bf16)b.z, (bf16)b.w };
  *(bf16x8*)(dst + i) = o;
}

// ---------------------------------------------------------------------------
// GEMM: C[m][n] = sum_k A[m][k] * W[n][k] + bias[n]   (B^T layout)
// M=4096, N=1024, K=1024. 128x128 tile, BK=32, 4 waves (2x2 of 64x64),
// 16x16x32 bf16 MFMA, global_load_lds staging (m97 structure).
// ---------------------------------------------------------------------------
template <typename OutT>
__device__ __forceinline__ void gemm_body(const bf16* __restrict__ A,
                                          const bf16* __restrict__ W,
                                          const float* __restrict__ bias,
                                          OutT* __restrict__ C)
{
  constexpr int K = 1024;
  __shared__ __align__(16) bf16 lA[128 * 32];
  __shared__ __align__(16) bf16 lB[128 * 32];

  const int tid  = threadIdx.x;
  const int lane = tid & 63;
  const int w    = tid >> 6;
  const int quad = lane >> 4;
  const int l16  = lane & 15;
  const int wr   = w >> 1, wc = w & 1;
  const int row0 = blockIdx.y * 128;
  const int col0 = blockIdx.x * 128;

  f32x4 acc[4][4] = {};

  const int c0 = tid, c1 = tid + 256;
  const bf16* Ab0 = A + (size_t)(row0 + (c0 >> 2)) * K + (c0 & 3) * 8;
  const bf16* Ab1 = A + (size_t)(row0 + (c1 >> 2)) * K + (c1 & 3) * 8;
  const bf16* Bb0 = W + (size_t)(col0 + (c0 >> 2)) * K + (c0 & 3) * 8;
  const bf16* Bb1 = W + (size_t)(col0 + (c1 >> 2)) * K + (c1 & 3) * 8;
  bf16* lA0 = &lA[c0 * 8]; bf16* lA1 = &lA[c1 * 8];
  bf16* lB0 = &lB[c0 * 8]; bf16* lB1 = &lB[c1 * 8];

  for (int kt = 0; kt < K; kt += 32) {
    __syncthreads();
    gload16(Ab0 + kt, lA0);
    gload16(Ab1 + kt, lA1);
    gload16(Bb0 + kt, lB0);
    gload16(Bb1 + kt, lB1);
    __syncthreads();

    bf16x8 af[4], bfrag[4];
#pragma unroll
    for (int mi = 0; mi < 4; mi++)
      af[mi] = *(const bf16x8*)&lA[(wr * 64 + mi * 16 + l16) * 32 + quad * 8];
#pragma unroll
    for (int ni = 0; ni < 4; ni++)
      bfrag[ni] = *(const bf16x8*)&lB[(wc * 64 + ni * 16 + l16) * 32 + quad * 8];
#pragma unroll
    for (int mi = 0; mi < 4; mi++)
#pragma unroll
      for (int ni = 0; ni < 4; ni++)
        acc[mi][ni] = __builtin_amdgcn_mfma_f32_16x16x32_bf16(
            af[mi], bfrag[ni], acc[mi][ni], 0, 0, 0);
  }

#pragma unroll
  for (int mi = 0; mi < 4; mi++) {
#pragma unroll
    for (int ni = 0; ni < 4; ni++) {
      const int gcol = col0 + wc * 64 + ni * 16 + l16;
      const float bv = bias[gcol];
#pragma unroll
      for (int r = 0; r < 4; r++) {
        const int grow = row0 + wr * 64 + mi * 16 + quad * 4 + r;
        C[(size_t)grow * 1024 + gcol] = (OutT)(acc[mi][ni][r] + bv);
      }
    }
  }
}

__global__ __launch_bounds__(256) void gemm_qkv_kernel(
    const bf16* xq, const bf16* xk, const bf16* xv,
    const bf16* wq, const bf16* wk, const bf16* wv,
    const float* bq, const float* bk, const float* bv,
    bf16* q, bf16* k, bf16* v)
{
  const bf16 *A, *W; const float* bias; bf16* C;
  if (blockIdx.z == 0)      { A = xq; W = wq; bias = bq; C = q; }
  else if (blockIdx.z == 1) { A = xk; W = wk; bias = bk; C = k; }
  else                      { A = xv; W = wv; bias = bv; C = v; }
  gemm_body<bf16>(A, W, bias, C);
}

__global__ __launch_bounds__(256) void gemm_out_kernel(
    const bf16* A, const bf16* W, const float* bias, float* C)
{
  gemm_body<float>(A, W, bias, C);
}

// ---------------------------------------------------------------------------
// V transpose into per-branch sparse-contiguous layout: vt_b[seg][h][d][kj].
// ---------------------------------------------------------------------------
__global__ __launch_bounds__(256) void vtrans_kernel(
    const bf16* __restrict__ v, bf16* vt0, bf16* vt1, bf16* vt2)
{
  __shared__ __align__(16) bf16 ltile[64 * 72];   // [kj][d], padded
  const int bid = blockIdx.x;
  int sl, dr, rem, shift; bf16* vt;
  if (bid < 1024)      { sl = 1024; dr = 1; rem = bid;        vt = vt0; shift = 4; }
  else if (bid < 1536) { sl = 2048; dr = 2; rem = bid - 1024; vt = vt1; shift = 3; }
  else                 { sl = 4096; dr = 4; rem = bid - 1536; vt = vt2; shift = 2; }
  const int ktile = rem & 15;
  const int h     = (rem >> 4) & 15;
  const int seg   = rem >> 8;
  const int grp   = h >> shift;          // h / (16/dr)
  const int segbase = seg * sl;
  const int tid = threadIdx.x;
  {
    const int i = tid >> 2, dc = tid & 3;
    const size_t p = (size_t)(segbase + (ktile * 64 + i) * dr + grp);
    const bf16* src = v + p * EDIM + h * 64 + dc * 16;
    *(uint4*)&ltile[i * 72 + dc * 16]     = *(const uint4*)(src);
    *(uint4*)&ltile[i * 72 + dc * 16 + 8] = *(const uint4*)(src + 8);
  }
  __syncthreads();
  {
    const int d = tid >> 2, kc = tid & 3;
    __align__(16) bf16 tmp[16];
#pragma unroll
    for (int j = 0; j < 16; j++) tmp[j] = ltile[(kc * 16 + j) * 72 + d];
    bf16* dst = vt + ((size_t)(seg * NH + h) * 64 + d) * GLEN + ktile * 64 + kc * 16;
    *(uint4*)dst       = *(uint4*)&tmp[0];
    *(uint4*)(dst + 8) = *(uint4*)&tmp[8];
  }
}

// ---------------------------------------------------------------------------
// Flash attention, transposed-S form. Block = (branch, seg, h, q-tile of 64).
// Wave w owns q rows [w*16, w*16+16); lane l16 = its q column.
// S^T = K Q^T (16x16x32 MFMA), P^T stays in registers as the B-operand of
// O^T = V^T P^T (16x16x16 MFMA). Double-buffered K/V staging, 1 barrier/iter.
// ---------------------------------------------------------------------------
__global__ __launch_bounds__(256) void attn_kernel(
    const bf16* __restrict__ qg, const bf16* __restrict__ kg,
    const bf16* vt0, const bf16* vt1, const bf16* vt2,
    bf16* o0, bf16* o1, bf16* o2,
    float* l0, float* l1, float* l2)
{
  __shared__ __align__(16) bf16 lK[2][64 * 64];     // [kj][d]
  __shared__ __align__(16) bf16 lV[2][64 * 64];     // [d][kj]

  const int bid = blockIdx.x;
  int sl, dr, rem, shift;
  const bf16* vt; bf16* ob; float* lseb;
  if (bid < 1024)      { sl = 1024; dr = 1; rem = bid;        vt = vt0; ob = o0; lseb = l0; shift = 4; }
  else if (bid < 1536) { sl = 2048; dr = 2; rem = bid - 1024; vt = vt1; ob = o1; lseb = l1; shift = 3; }
  else                 { sl = 4096; dr = 4; rem = bid - 1536; vt = vt2; ob = o2; lseb = l2; shift = 2; }
  const int qt  = 15 - (rem & 15);       // qt-descending: long blocks launch first
  const int h   = (rem >> 4) & 15;
  const int seg = rem >> 8;
  const int grp = h >> shift;
  const int segbase = seg * sl;

  const int tid = threadIdx.x, lane = tid & 63, w = tid >> 6;
  const int quad = lane >> 4, l16 = lane & 15;
  const int qs0 = qt * 64;

  // Q fragment (B-operand of S^T MFMA): B[k=d=quad*8+j][n=q=l16]
  bf16x8 qa0, qa1;
  {
    const int qi = qs0 + w * 16 + l16;
    const size_t p = (size_t)(segbase + qi * dr + grp);
    const bf16* qp = qg + p * EDIM + h * 64 + quad * 8;
    qa0 = *(const bf16x8*)(qp);
    qa1 = *(const bf16x8*)(qp + 32);
  }

  f32x4 Oa[4] = {};                  // O^T frags: col l16=q, row = d (nf*16+quad*4+r)
  float m_r = -__builtin_inff(), l_r = 0.f;

  const bf16* vbase = vt + (size_t)(seg * NH + h) * 64 * GLEN;
  const int c0 = tid, c1 = tid + 256;

  auto stage = [&](int kt, int buf) {
    const bf16* kp0 = kg + (size_t)(segbase + (kt * 64 + (c0 >> 3)) * dr + grp) * EDIM + h * 64 + (c0 & 7) * 8;
    const bf16* kp1 = kg + (size_t)(segbase + (kt * 64 + (c1 >> 3)) * dr + grp) * EDIM + h * 64 + (c1 & 7) * 8;
    gload16(kp0, &lK[buf][c0 * 8]);
    gload16(kp1, &lK[buf][c1 * 8]);
    const bf16* vp0 = vbase + (size_t)(c0 >> 3) * GLEN + kt * 64 + (c0 & 7) * 8;
    const bf16* vp1 = vbase + (size_t)(c1 >> 3) * GLEN + kt * 64 + (c1 & 7) * 8;
    gload16(vp0, &lV[buf][c0 * 8]);
    gload16(vp1, &lV[buf][c1 * 8]);
  };

  stage(0, 0);

  const int qi_lane = qs0 + w * 16 + l16;   // this lane's q row (global in segment)

  for (int kt = 0; kt <= qt; kt++) {
    __syncthreads();                 // tile kt resident (vmcnt drain); prev reads done
    if (kt < qt) stage(kt + 1, (kt + 1) & 1);
    const bf16* bK = lK[kt & 1];
    const bf16* bV = lV[kt & 1];

    const bool diag = (kt == qt);
    const int tmax = diag ? w : 3;

    // S^T = K Q^T: A[m=kpos=t*16+l16][k=d], B=Q. D: col=l16=q, row=quad*4+r=kpos
    f32x4 s[4];
#pragma unroll
    for (int t = 0; t < 4; t++) {
      if (t <= tmax) {
        s[t] = f32x4{0.f, 0.f, 0.f, 0.f};
        bf16x8 ka0 = *(const bf16x8*)&bK[(t * 16 + l16) * 64 + quad * 8];
        bf16x8 ka1 = *(const bf16x8*)&bK[(t * 16 + l16) * 64 + 32 + quad * 8];
        s[t] = __builtin_amdgcn_mfma_f32_16x16x32_bf16(ka0, qa0, s[t], 0, 0, 0);
        s[t] = __builtin_amdgcn_mfma_f32_16x16x32_bf16(ka1, qa1, s[t], 0, 0, 0);
      }
    }

    // per-lane online softmax over this tile's kpos values
    float p[4][4];
    float mloc = -__builtin_inff();
#pragma unroll
    for (int t = 0; t < 4; t++) {
      if (t <= tmax) {
#pragma unroll
        for (int r = 0; r < 4; r++) {
          float sv = s[t][r] * 0.125f;               // 1/sqrt(64)
          if (diag) {
            const int kj = kt * 64 + t * 16 + quad * 4 + r;
            if (kj > qi_lane) sv = -__builtin_inff();
          }
          p[t][r] = sv;
          mloc = fmaxf(mloc, sv);
        }
      }
    }
    mloc = fmaxf(mloc, __shfl_xor(mloc, 16, 64));
    mloc = fmaxf(mloc, __shfl_xor(mloc, 32, 64));
    const float mnew  = fmaxf(m_r, mloc);
    const float alpha = __expf(m_r - mnew);
    m_r = mnew;

    bf16x4 pb[4];
    float rs = 0.f;
#pragma unroll
    for (int t = 0; t < 4; t++) {
      if (t <= tmax) {
#pragma unroll
        for (int r = 0; r < 4; r++) {
          const float pv = __expf(p[t][r] - mnew);
          pb[t][r] = (bf16)pv;
          rs += pv;
        }
      }
    }
    rs += __shfl_xor(rs, 16, 64);
    rs += __shfl_xor(rs, 32, 64);
    l_r = l_r * alpha + rs;

#pragma unroll
    for (int nf = 0; nf < 4; nf++) {
#pragma unroll
      for (int r = 0; r < 4; r++) Oa[nf][r] *= alpha;
    }

    // O^T += V^T P^T: A[m=d=nf*16+l16][k=quad*4+j] from lV[d][kj]; B = pb
#pragma unroll
    for (int t = 0; t < 4; t++) {
      if (t <= tmax) {
#pragma unroll
        for (int nf = 0; nf < 4; nf++) {
          bf16x4 va = *(const bf16x4*)&bV[(nf * 16 + l16) * 64 + t * 16 + quad * 4];
          Oa[nf] = mfma16x16x16_bf16(va, pb[t], Oa[nf]);
        }
      }
    }
  }

  // epilogue: lane l16 owns q column; d = nf*16 + quad*4 + r (4 contiguous)
  const float linv = 1.0f / l_r;
  const int pdense = segbase + qi_lane * dr + grp;
  bf16* orow = ob + (size_t)pdense * EDIM + h * 64;
#pragma unroll
  for (int nf = 0; nf < 4; nf++) {
    bf16x4 ov;
#pragma unroll
    for (int r = 0; r < 4; r++) ov[r] = (bf16)(Oa[nf][r] * linv);
    *(bf16x4*)(orow + nf * 16 + quad * 4) = ov;
  }
  if (quad == 0)
    lseb[h * L_SEQ + pdense] = m_r + __logf(l_r);
}

// ---------------------------------------------------------------------------
// Merge: softmax over branch lse at each (h,p); coverage computed analytically.
// ---------------------------------------------------------------------------
__global__ __launch_bounds__(256) void merge_kernel(
    const bf16* __restrict__ o0, const bf16* __restrict__ o1, const bf16* __restrict__ o2,
    const float* __restrict__ l0, const float* __restrict__ l1, const float* __restrict__ l2,
    bf16* __restrict__ merged)
{
  const int idx = blockIdx.x * 256 + threadIdx.x;   // over L*H*8
  const int dc = idx & 7;
  const int h  = (idx >> 3) & 15;
  const int p  = idx >> 7;
  const bool c1 = ((p & 1) == (h >> 3));   // branch dr=2 coverage
  const bool c2 = ((p & 3) == (h >> 2));   // branch dr=4 coverage
  const float s0 = l0[h * L_SEQ + p];
  const float s1 = c1 ? l1[h * L_SEQ + p] : -__builtin_inff();
  const float s2 = c2 ? l2[h * L_SEQ + p] : -__builtin_inff();
  const float mx = fmaxf(s0, fmaxf(s1, s2));
  float w0 = __expf(s0 - mx);
  float w1 = c1 ? __expf(s1 - mx) : 0.f;
  float w2 = c2 ? __expf(s2 - mx) : 0.f;
  const float inv = 1.0f / (w0 + w1 + w2);
  w0 *= inv; w1 *= inv; w2 *= inv;

  const size_t off = (size_t)p * EDIM + h * 64 + dc * 8;
  float acc[8];
  bf16x8 a0 = *(const bf16x8*)(o0 + off);
#pragma unroll
  for (int j = 0; j < 8; j++) acc[j] = w0 * (float)a0[j];
  if (c1) {
    bf16x8 a1 = *(const bf16x8*)(o1 + off);
#pragma unroll
    for (int j = 0; j < 8; j++) acc[j] += w1 * (float)a1[j];
  }
  if (c2) {
    bf16x8 a2 = *(const bf16x8*)(o2 + off);
#pragma unroll
    for (int j = 0; j < 8; j++) acc[j] += w2 * (float)a2[j];
  }
  bf16x8 r;
#pragma unroll
  for (int j = 0; j < 8; j++) r[j] = (bf16)acc[j];
  *(bf16x8*)(merged + off) = r;
}

// ---------------------------------------------------------------------------
extern "C" void kernel_launch(void* const* d_in, const int* in_sizes, int n_in,
                              void* d_out, int out_size, void* d_ws, size_t ws_size,
                              hipStream_t stream)
{
  (void)in_sizes; (void)n_in; (void)out_size; (void)ws_size;
  const float* query = (const float*)d_in[0];
  const float* key   = (const float*)d_in[1];
  const float* value = (const float*)d_in[2];
  const float* Wq = (const float*)d_in[3];
  const float* bq = (const float*)d_in[4];
  const float* Wk = (const float*)d_in[5];
  const float* bk = (const float*)d_in[6];
  const float* Wv = (const float*)d_in[7];
  const float* bv = (const float*)d_in[8];
  const float* Wo = (const float*)d_in[9];
  const float* bo = (const float*)d_in[10];

  char* base = (char*)d_ws;
  size_t off = 0;
  auto take = [&](size_t nbytes) -> char* {
    char* p = base + off;
    off += (nbytes + 255) & ~(size_t)255;
    return p;
  };
  const size_t LE2 = (size_t)L_SEQ * EDIM * 2;
  const size_t EE2 = (size_t)EDIM * EDIM * 2;
  bf16* xq  = (bf16*)take(LE2);
  bf16* xk  = (bf16*)take(LE2);
  bf16* xv  = (bf16*)take(LE2);
  bf16* wqb = (bf16*)take(EE2);
  bf16* wkb = (bf16*)take(EE2);
  bf16* wvb = (bf16*)take(EE2);
  bf16* wob = (bf16*)take(EE2);
  bf16* qb  = (bf16*)take(LE2);
  bf16* kb  = (bf16*)take(LE2);
  bf16* vb  = (bf16*)take(LE2);
  bf16* vt0 = (bf16*)take((size_t)4 * NH * HD * GLEN * 2);
  bf16* vt1 = (bf16*)take((size_t)2 * NH * HD * GLEN * 2);
  bf16* vt2 = (bf16*)take((size_t)1 * NH * HD * GLEN * 2);
  float* lse0 = (float*)take((size_t)NH * L_SEQ * 4);
  float* lse1 = (float*)take((size_t)NH * L_SEQ * 4);
  float* lse2 = (float*)take((size_t)NH * L_SEQ * 4);
  bf16* merged = (bf16*)take(LE2);
  // branch outputs alias the converted inputs (dead after gemm_qkv)
  bf16* o0 = xq; bf16* o1 = xk; bf16* o2 = xv;

  dim3 blk(256);
  cvt_kernel<<<dim3(2048, 7), blk, 0, stream>>>(
      query, key, value, Wq, Wk, Wv, Wo, xq, xk, xv, wqb, wkb, wvb, wob);
  gemm_qkv_kernel<<<dim3(8, 32, 3), blk, 0, stream>>>(
      xq, xk, xv, wqb, wkb, wvb, bq, bk, bv, qb, kb, vb);
  vtrans_kernel<<<dim3(1792), blk, 0, stream>>>(vb, vt0, vt1, vt2);
  attn_kernel<<<dim3(1792), blk, 0, stream>>>(
      qb, kb, vt0, vt1, vt2, o0, o1, o2, lse0, lse1, lse2);
  merge_kernel<<<dim3(2048), blk, 0, stream>>>(
      o0, o1, o2, lse0, lse1, lse2, merged);
  gemm_out_kernel<<<dim3(8, 32), blk, 0, stream>>>(merged, wob, bo, (float*)d_out);
}

// Round 4
// 258.320 us; speedup vs baseline: 1.6302x; 1.6302x over previous
//
#include <hip/hip_runtime.h>
#include <math.h>

// DilatedAttention on MI355X (gfx950), bf16 MFMA implementation.
// L=4096, E=1024, H=16, D=64. Branches (sl,dr) = (1024,1),(2048,2),(4096,4).
// Every branch reduces to causal attention over g=1024 sparse positions.
//
// Attention in transposed-S form:
//   S^T = K Q^T  (lane l16 = q column)  -> softmax reduces with 4 shuffles
//   O^T = V^T P^T with 16x16x16 MFMA    -> P^T registers are the B-operand.
// R4: XOR-swizzled LDS tiles (chunk c of row r at slot c^(r&7)) implemented
// via staging-source permutation (global_load_lds dest is lane-fixed), killing
// the 16-way bank conflicts that caused R3's 6.15e7 conflict cycles.

#define L_SEQ 4096
#define EDIM  1024
#define NH    16
#define HD    64
#define GLEN  1024

typedef __bf16 bf16;
typedef __bf16 bf16x8 __attribute__((ext_vector_type(8)));
typedef __bf16 bf16x4 __attribute__((ext_vector_type(4)));
typedef short  s16x4  __attribute__((ext_vector_type(4)));
typedef float  f32x4  __attribute__((ext_vector_type(4)));

// async global->LDS, 16B per lane. LDS dest semantics: wave-uniform base + lane*16.
__device__ __forceinline__ void gload16(const bf16* g, bf16* l) {
  __builtin_amdgcn_global_load_lds(
      (__attribute__((address_space(1))) void*)(const_cast<bf16*>(g)),
      (__attribute__((address_space(3))) void*)(l),
      16, 0, 0);
}

// v_mfma_f32_16x16x16_bf16 (builtin name only exists in the device pass).
__device__ __forceinline__ f32x4 mfma16x16x16_bf16(bf16x4 a, bf16x4 b, f32x4 c) {
#if defined(__HIP_DEVICE_COMPILE__)
  union { bf16x4 h; s16x4 s; } ua, ub;
  ua.h = a; ub.h = b;
  return __builtin_amdgcn_mfma_f32_16x16x16bf16_1k(ua.s, ub.s, c, 0, 0, 0);
#else
  (void)a; (void)b;
  return c;   // host stub, never executed
#endif
}

// ---------------------------------------------------------------------------
// fp32 -> bf16 conversion for query/key/value (L*E) and Wq/Wk/Wv/Wo (E*E)
// ---------------------------------------------------------------------------
__global__ __launch_bounds__(256) void cvt_kernel(
    const float* q, const float* k, const float* v,
    const float* wq, const float* wk, const float* wv, const float* wo,
    bf16* oq, bf16* ok, bf16* ov,
    bf16* owq, bf16* owk, bf16* owv, bf16* owo)
{
  const float* src; bf16* dst; int n;
  switch (blockIdx.y) {
    case 0: src = q;  dst = oq;  n = L_SEQ*EDIM; break;
    case 1: src = k;  dst = ok;  n = L_SEQ*EDIM; break;
    case 2: src = v;  dst = ov;  n = L_SEQ*EDIM; break;
    case 3: src = wq; dst = owq; n = EDIM*EDIM; break;
    case 4: src = wk; dst = owk; n = EDIM*EDIM; break;
    case 5: src = wv; dst = owv; n = EDIM*EDIM; break;
    default: src = wo; dst = owo; n = EDIM*EDIM; break;
  }
  int i = (blockIdx.x * 256 + threadIdx.x) * 8;
  if (i >= n) return;
  const float4* s4 = (const float4*)(src + i);
  float4 a = s4[0], b = s4[1];
  bf16x8 o = { (bf16)a.x, (bf16)a.y, (bf16)a.z, (bf16)a.w,
               (bf16)b.x, (bf16)b.y, (bf16)b.z, (bf16)b.w };
  *(bf16x8*)(dst + i) = o;
}

// ---------------------------------------------------------------------------
// GEMM: C[m][n] = sum_k A[m][k] * W[n][k] + bias[n]   (B^T layout)
// M=4096, N=1024, K=1024. 128x128 tile, BK=32, 4 waves (2x2 of 64x64),
// 16x16x32 bf16 MFMA, global_load_lds staging (m97 structure).
// ---------------------------------------------------------------------------
template <typename OutT>
__device__ __forceinline__ void gemm_body(const bf16* __restrict__ A,
                                          const bf16* __restrict__ W,
                                          const float* __restrict__ bias,
                                          OutT* __restrict__ C)
{
  constexpr int K = 1024;
  __shared__ __align__(16) bf16 lA[128 * 32];
  __shared__ __align__(16) bf16 lB[128 * 32];

  const int tid  = threadIdx.x;
  const int lane = tid & 63;
  const int w    = tid >> 6;
  const int quad = lane >> 4;
  const int l16  = lane & 15;
  const int wr   = w >> 1, wc = w & 1;
  const int row0 = blockIdx.y * 128;
  const int col0 = blockIdx.x * 128;

  f32x4 acc[4][4] = {};

  const int c0 = tid, c1 = tid + 256;
  const bf16* Ab0 = A + (size_t)(row0 + (c0 >> 2)) * K + (c0 & 3) * 8;
  const bf16* Ab1 = A + (size_t)(row0 + (c1 >> 2)) * K + (c1 & 3) * 8;
  const bf16* Bb0 = W + (size_t)(col0 + (c0 >> 2)) * K + (c0 & 3) * 8;
  const bf16* Bb1 = W + (size_t)(col0 + (c1 >> 2)) * K + (c1 & 3) * 8;
  bf16* lA0 = &lA[c0 * 8]; bf16* lA1 = &lA[c1 * 8];
  bf16* lB0 = &lB[c0 * 8]; bf16* lB1 = &lB[c1 * 8];

  for (int kt = 0; kt < K; kt += 32) {
    __syncthreads();
    gload16(Ab0 + kt, lA0);
    gload16(Ab1 + kt, lA1);
    gload16(Bb0 + kt, lB0);
    gload16(Bb1 + kt, lB1);
    __syncthreads();

    bf16x8 af[4], bfrag[4];
#pragma unroll
    for (int mi = 0; mi < 4; mi++)
      af[mi] = *(const bf16x8*)&lA[(wr * 64 + mi * 16 + l16) * 32 + quad * 8];
#pragma unroll
    for (int ni = 0; ni < 4; ni++)
      bfrag[ni] = *(const bf16x8*)&lB[(wc * 64 + ni * 16 + l16) * 32 + quad * 8];
#pragma unroll
    for (int mi = 0; mi < 4; mi++)
#pragma unroll
      for (int ni = 0; ni < 4; ni++)
        acc[mi][ni] = __builtin_amdgcn_mfma_f32_16x16x32_bf16(
            af[mi], bfrag[ni], acc[mi][ni], 0, 0, 0);
  }

#pragma unroll
  for (int mi = 0; mi < 4; mi++) {
#pragma unroll
    for (int ni = 0; ni < 4; ni++) {
      const int gcol = col0 + wc * 64 + ni * 16 + l16;
      const float bv = bias[gcol];
#pragma unroll
      for (int r = 0; r < 4; r++) {
        const int grow = row0 + wr * 64 + mi * 16 + quad * 4 + r;
        C[(size_t)grow * 1024 + gcol] = (OutT)(acc[mi][ni][r] + bv);
      }
    }
  }
}

__global__ __launch_bounds__(256) void gemm_qkv_kernel(
    const bf16* xq, const bf16* xk, const bf16* xv,
    const bf16* wq, const bf16* wk, const bf16* wv,
    const float* bq, const float* bk, const float* bv,
    bf16* q, bf16* k, bf16* v)
{
  const bf16 *A, *W; const float* bias; bf16* C;
  if (blockIdx.z == 0)      { A = xq; W = wq; bias = bq; C = q; }
  else if (blockIdx.z == 1) { A = xk; W = wk; bias = bk; C = k; }
  else                      { A = xv; W = wv; bias = bv; C = v; }
  gemm_body<bf16>(A, W, bias, C);
}

__global__ __launch_bounds__(256) void gemm_out_kernel(
    const bf16* A, const bf16* W, const float* bias, float* C)
{
  gemm_body<float>(A, W, bias, C);
}

// ---------------------------------------------------------------------------
// V transpose into per-branch sparse-contiguous layout: vt_b[seg][h][d][kj].
// ---------------------------------------------------------------------------
__global__ __launch_bounds__(256) void vtrans_kernel(
    const bf16* __restrict__ v, bf16* vt0, bf16* vt1, bf16* vt2)
{
  __shared__ __align__(16) bf16 ltile[64 * 72];   // [kj][d], padded
  const int bid = blockIdx.x;
  int sl, dr, rem, shift; bf16* vt;
  if (bid < 1024)      { sl = 1024; dr = 1; rem = bid;        vt = vt0; shift = 4; }
  else if (bid < 1536) { sl = 2048; dr = 2; rem = bid - 1024; vt = vt1; shift = 3; }
  else                 { sl = 4096; dr = 4; rem = bid - 1536; vt = vt2; shift = 2; }
  const int ktile = rem & 15;
  const int h     = (rem >> 4) & 15;
  const int seg   = rem >> 8;
  const int grp   = h >> shift;          // h / (16/dr)
  const int segbase = seg * sl;
  const int tid = threadIdx.x;
  {
    const int i = tid >> 2, dc = tid & 3;
    const size_t p = (size_t)(segbase + (ktile * 64 + i) * dr + grp);
    const bf16* src = v + p * EDIM + h * 64 + dc * 16;
    *(uint4*)&ltile[i * 72 + dc * 16]     = *(const uint4*)(src);
    *(uint4*)&ltile[i * 72 + dc * 16 + 8] = *(const uint4*)(src + 8);
  }
  __syncthreads();
  {
    const int d = tid >> 2, kc = tid & 3;
    __align__(16) bf16 tmp[16];
#pragma unroll
    for (int j = 0; j < 16; j++) tmp[j] = ltile[(kc * 16 + j) * 72 + d];
    bf16* dst = vt + ((size_t)(seg * NH + h) * 64 + d) * GLEN + ktile * 64 + kc * 16;
    *(uint4*)dst       = *(uint4*)&tmp[0];
    *(uint4*)(dst + 8) = *(uint4*)&tmp[8];
  }
}

// ---------------------------------------------------------------------------
// Flash attention, transposed-S form with XOR-swizzled LDS tiles.
// Block = (branch, seg, h, q-tile of 64). Wave w owns q rows [w*16, w*16+16);
// lane l16 = its q column. Double-buffered K/V staging, 1 barrier/iter.
// LDS tile layout (both lK [kj][d] and lV [d][kj]): 16B chunk c of row r is
// stored at chunk slot (c ^ (r & 7)) within the row -> column reads across 16
// rows spread over all 8 bank groups (2 lanes/bank = free).
// ---------------------------------------------------------------------------
__global__ __launch_bounds__(256) void attn_kernel(
    const bf16* __restrict__ qg, const bf16* __restrict__ kg,
    const bf16* vt0, const bf16* vt1, const bf16* vt2,
    bf16* o0, bf16* o1, bf16* o2,
    float* l0, float* l1, float* l2)
{
  __shared__ __align__(16) bf16 lK[2][64 * 64];     // [kj][d], swizzled
  __shared__ __align__(16) bf16 lV[2][64 * 64];     // [d][kj], swizzled

  const int bid = blockIdx.x;
  int sl, dr, rem, shift;
  const bf16* vt; bf16* ob; float* lseb;
  if (bid < 1024)      { sl = 1024; dr = 1; rem = bid;        vt = vt0; ob = o0; lseb = l0; shift = 4; }
  else if (bid < 1536) { sl = 2048; dr = 2; rem = bid - 1024; vt = vt1; ob = o1; lseb = l1; shift = 3; }
  else                 { sl = 4096; dr = 4; rem = bid - 1536; vt = vt2; ob = o2; lseb = l2; shift = 2; }
  const int qt  = 15 - (rem & 15);       // qt-descending: long blocks launch first
  const int h   = (rem >> 4) & 15;
  const int seg = rem >> 8;
  const int grp = h >> shift;
  const int segbase = seg * sl;

  const int tid = threadIdx.x, lane = tid & 63, w = tid >> 6;
  const int quad = lane >> 4, l16 = lane & 15;
  const int qs0 = qt * 64;

  // Q fragment (B-operand of S^T MFMA): B[k=d=quad*8+j][n=q=l16]
  bf16x8 qa0, qa1;
  {
    const int qi = qs0 + w * 16 + l16;
    const size_t p = (size_t)(segbase + qi * dr + grp);
    const bf16* qp = qg + p * EDIM + h * 64 + quad * 8;
    qa0 = *(const bf16x8*)(qp);
    qa1 = *(const bf16x8*)(qp + 32);
  }

  f32x4 Oa[4] = {};                  // O^T frags: col l16=q, row = d (nf*16+quad*4+r)
  float m_r = -__builtin_inff(), l_r = 0.f;

  const bf16* vbase = vt + (size_t)(seg * NH + h) * 64 * GLEN;
  const int c0 = tid, c1 = tid + 256;
  // staging-source permutation implementing the XOR swizzle:
  // LDS chunk position p (=c0/c1) is row r=p>>3, slot s=p&7; it must receive
  // global chunk c = s ^ (r & 7).
  const int r0 = c0 >> 3, sw0 = ((c0 & 7) ^ (r0 & 7));
  const int r1 = c1 >> 3, sw1 = ((c1 & 7) ^ (r1 & 7));

  auto stage = [&](int kt, int buf) {
    // K tile: row = kj, chunk = d-chunk
    const bf16* kp0 = kg + (size_t)(segbase + (kt * 64 + r0) * dr + grp) * EDIM + h * 64 + sw0 * 8;
    const bf16* kp1 = kg + (size_t)(segbase + (kt * 64 + r1) * dr + grp) * EDIM + h * 64 + sw1 * 8;
    gload16(kp0, &lK[buf][c0 * 8]);
    gload16(kp1, &lK[buf][c1 * 8]);
    // V tile: row = d, chunk = kj-chunk
    const bf16* vp0 = vbase + (size_t)r0 * GLEN + kt * 64 + sw0 * 8;
    const bf16* vp1 = vbase + (size_t)r1 * GLEN + kt * 64 + sw1 * 8;
    gload16(vp0, &lV[buf][c0 * 8]);
    gload16(vp1, &lV[buf][c1 * 8]);
  };

  stage(0, 0);

  const int qi_lane = qs0 + w * 16 + l16;   // this lane's q row (global in segment)

  for (int kt = 0; kt <= qt; kt++) {
    __syncthreads();                 // tile kt resident (vmcnt drain); prev reads done
    if (kt < qt) stage(kt + 1, (kt + 1) & 1);
    const bf16* bK = lK[kt & 1];
    const bf16* bV = lV[kt & 1];

    const bool diag = (kt == qt);
    const int tmax = diag ? w : 3;

    // S^T = K Q^T: A[m=kpos=t*16+l16][k=d], B=Q. D: col=l16=q, row=quad*4+r=kpos
    f32x4 s[4];
#pragma unroll
    for (int t = 0; t < 4; t++) {
      if (t <= tmax) {
        s[t] = f32x4{0.f, 0.f, 0.f, 0.f};
        const int kj = t * 16 + l16;
        const int rs = kj & 7;
        bf16x8 ka0 = *(const bf16x8*)&bK[kj * 64 + ((quad       ^ rs) * 8)];
        bf16x8 ka1 = *(const bf16x8*)&bK[kj * 64 + (((4 + quad) ^ rs) * 8)];
        s[t] = __builtin_amdgcn_mfma_f32_16x16x32_bf16(ka0, qa0, s[t], 0, 0, 0);
        s[t] = __builtin_amdgcn_mfma_f32_16x16x32_bf16(ka1, qa1, s[t], 0, 0, 0);
      }
    }

    // per-lane online softmax over this tile's kpos values
    float p[4][4];
    float mloc = -__builtin_inff();
#pragma unroll
    for (int t = 0; t < 4; t++) {
      if (t <= tmax) {
#pragma unroll
        for (int r = 0; r < 4; r++) {
          float sv = s[t][r] * 0.125f;               // 1/sqrt(64)
          if (diag) {
            const int kj = kt * 64 + t * 16 + quad * 4 + r;
            if (kj > qi_lane) sv = -__builtin_inff();
          }
          p[t][r] = sv;
          mloc = fmaxf(mloc, sv);
        }
      }
    }
    mloc = fmaxf(mloc, __shfl_xor(mloc, 16, 64));
    mloc = fmaxf(mloc, __shfl_xor(mloc, 32, 64));
    const float mnew  = fmaxf(m_r, mloc);
    const float alpha = __expf(m_r - mnew);
    m_r = mnew;

    bf16x4 pb[4];
    float rs_sum = 0.f;
#pragma unroll
    for (int t = 0; t < 4; t++) {
      if (t <= tmax) {
#pragma unroll
        for (int r = 0; r < 4; r++) {
          const float pv = __expf(p[t][r] - mnew);
          pb[t][r] = (bf16)pv;
          rs_sum += pv;
        }
      }
    }
    rs_sum += __shfl_xor(rs_sum, 16, 64);
    rs_sum += __shfl_xor(rs_sum, 32, 64);
    l_r = l_r * alpha + rs_sum;

#pragma unroll
    for (int nf = 0; nf < 4; nf++) {
#pragma unroll
      for (int r = 0; r < 4; r++) Oa[nf][r] *= alpha;
    }

    // O^T += V^T P^T: A[m=d=nf*16+l16][k=kpos=t*16+quad*4+j] from swizzled lV
#pragma unroll
    for (int t = 0; t < 4; t++) {
      if (t <= tmax) {
        const int ck  = 2 * t + (quad >> 1);     // 16B kpos-chunk
        const int sub = (quad & 1) * 4;          // element offset within chunk
#pragma unroll
        for (int nf = 0; nf < 4; nf++) {
          const int drow = nf * 16 + l16;
          bf16x4 va = *(const bf16x4*)&bV[drow * 64 + ((ck ^ (drow & 7)) * 8) + sub];
          Oa[nf] = mfma16x16x16_bf16(va, pb[t], Oa[nf]);
        }
      }
    }
  }

  // epilogue: lane l16 owns q column; d = nf*16 + quad*4 + r (4 contiguous)
  const float linv = 1.0f / l_r;
  const int pdense = segbase + qi_lane * dr + grp;
  bf16* orow = ob + (size_t)pdense * EDIM + h * 64;
#pragma unroll
  for (int nf = 0; nf < 4; nf++) {
    bf16x4 ov;
#pragma unroll
    for (int r = 0; r < 4; r++) ov[r] = (bf16)(Oa[nf][r] * linv);
    *(bf16x4*)(orow + nf * 16 + quad * 4) = ov;
  }
  if (quad == 0)
    lseb[h * L_SEQ + pdense] = m_r + __logf(l_r);
}

// ---------------------------------------------------------------------------
// Merge: softmax over branch lse at each (h,p); coverage computed analytically.
// ---------------------------------------------------------------------------
__global__ __launch_bounds__(256) void merge_kernel(
    const bf16* __restrict__ o0, const bf16* __restrict__ o1, const bf16* __restrict__ o2,
    const float* __restrict__ l0, const float* __restrict__ l1, const float* __restrict__ l2,
    bf16* __restrict__ merged)
{
  const int idx = blockIdx.x * 256 + threadIdx.x;   // over L*H*8
  const int dc = idx & 7;
  const int h  = (idx >> 3) & 15;
  const int p  = idx >> 7;
  const bool c1 = ((p & 1) == (h >> 3));   // branch dr=2 coverage
  const bool c2 = ((p & 3) == (h >> 2));   // branch dr=4 coverage
  const float s0 = l0[h * L_SEQ + p];
  const float s1 = c1 ? l1[h * L_SEQ + p] : -__builtin_inff();
  const float s2 = c2 ? l2[h * L_SEQ + p] : -__builtin_inff();
  const float mx = fmaxf(s0, fmaxf(s1, s2));
  float w0 = __expf(s0 - mx);
  float w1 = c1 ? __expf(s1 - mx) : 0.f;
  float w2 = c2 ? __expf(s2 - mx) : 0.f;
  const float inv = 1.0f / (w0 + w1 + w2);
  w0 *= inv; w1 *= inv; w2 *= inv;

  const size_t off = (size_t)p * EDIM + h * 64 + dc * 8;
  float acc[8];
  bf16x8 a0 = *(const bf16x8*)(o0 + off);
#pragma unroll
  for (int j = 0; j < 8; j++) acc[j] = w0 * (float)a0[j];
  if (c1) {
    bf16x8 a1 = *(const bf16x8*)(o1 + off);
#pragma unroll
    for (int j = 0; j < 8; j++) acc[j] += w1 * (float)a1[j];
  }
  if (c2) {
    bf16x8 a2 = *(const bf16x8*)(o2 + off);
#pragma unroll
    for (int j = 0; j < 8; j++) acc[j] += w2 * (float)a2[j];
  }
  bf16x8 r;
#pragma unroll
  for (int j = 0; j < 8; j++) r[j] = (bf16)acc[j];
  *(bf16x8*)(merged + off) = r;
}

// ---------------------------------------------------------------------------
extern "C" void kernel_launch(void* const* d_in, const int* in_sizes, int n_in,
                              void* d_out, int out_size, void* d_ws, size_t ws_size,
                              hipStream_t stream)
{
  (void)in_sizes; (void)n_in; (void)out_size; (void)ws_size;
  const float* query = (const float*)d_in[0];
  const float* key   = (const float*)d_in[1];
  const float* value = (const float*)d_in[2];
  const float* Wq = (const float*)d_in[3];
  const float* bq = (const float*)d_in[4];
  const float* Wk = (const float*)d_in[5];
  const float* bk = (const float*)d_in[6];
  const float* Wv = (const float*)d_in[7];
  const float* bv = (const float*)d_in[8];
  const float* Wo = (const float*)d_in[9];
  const float* bo = (const float*)d_in[10];

  char* base = (char*)d_ws;
  size_t off = 0;
  auto take = [&](size_t nbytes) -> char* {
    char* p = base + off;
    off += (nbytes + 255) & ~(size_t)255;
    return p;
  };
  const size_t LE2 = (size_t)L_SEQ * EDIM * 2;
  const size_t EE2 = (size_t)EDIM * EDIM * 2;
  bf16* xq  = (bf16*)take(LE2);
  bf16* xk  = (bf16*)take(LE2);
  bf16* xv  = (bf16*)take(LE2);
  bf16* wqb = (bf16*)take(EE2);
  bf16* wkb = (bf16*)take(EE2);
  bf16* wvb = (bf16*)take(EE2);
  bf16* wob = (bf16*)take(EE2);
  bf16* qb  = (bf16*)take(LE2);
  bf16* kb  = (bf16*)take(LE2);
  bf16* vb  = (bf16*)take(LE2);
  bf16* vt0 = (bf16*)take((size_t)4 * NH * HD * GLEN * 2);
  bf16* vt1 = (bf16*)take((size_t)2 * NH * HD * GLEN * 2);
  bf16* vt2 = (bf16*)take((size_t)1 * NH * HD * GLEN * 2);
  float* lse0 = (float*)take((size_t)NH * L_SEQ * 4);
  float* lse1 = (float*)take((size_t)NH * L_SEQ * 4);
  float* lse2 = (float*)take((size_t)NH * L_SEQ * 4);
  bf16* merged = (bf16*)take(LE2);
  // branch outputs alias the converted inputs (dead after gemm_qkv)
  bf16* o0 = xq; bf16* o1 = xk; bf16* o2 = xv;

  dim3 blk(256);
  cvt_kernel<<<dim3(2048, 7), blk, 0, stream>>>(
      query, key, value, Wq, Wk, Wv, Wo, xq, xk, xv, wqb, wkb, wvb, wob);
  gemm_qkv_kernel<<<dim3(8, 32, 3), blk, 0, stream>>>(
      xq, xk, xv, wqb, wkb, wvb, bq, bk, bv, qb, kb, vb);
  vtrans_kernel<<<dim3(1792), blk, 0, stream>>>(vb, vt0, vt1, vt2);
  attn_kernel<<<dim3(1792), blk, 0, stream>>>(
      qb, kb, vt0, vt1, vt2, o0, o1, o2, lse0, lse1, lse2);
  merge_kernel<<<dim3(2048), blk, 0, stream>>>(
      o0, o1, o2, lse0, lse1, lse2, merged);
  gemm_out_kernel<<<dim3(8, 32), blk, 0, stream>>>(merged, wob, bo, (float*)d_out);
}